// Round 3
// baseline (477.816 us; speedup 1.0000x reference)
//
#include <hip/hip_runtime.h>

#define NN 100000
#define EE 400000

typedef unsigned short u16;
typedef unsigned int u32;
typedef short short8 __attribute__((ext_vector_type(8)));
typedef __bf16 bf16x8 __attribute__((ext_vector_type(8)));
typedef float f32x4 __attribute__((ext_vector_type(4)));

__device__ __forceinline__ short8 pack_bf16x8(f32x4 lo, f32x4 hi) {
  bf16x8 r;
#pragma unroll
  for (int j = 0; j < 4; ++j) { r[j] = (__bf16)lo[j]; r[4 + j] = (__bf16)hi[j]; }
  return __builtin_bit_cast(short8, r);
}

__device__ __forceinline__ u16 f2bf(float f) {
  return __builtin_bit_cast(unsigned short, (__bf16)f);
}

__device__ __forceinline__ float bf2f(short s) {
  u32 b = ((u32)(unsigned short)s) << 16;
  return __builtin_bit_cast(float, b);
}

// ---------------------------------------------------------------------------
// K0: cast x (f32) -> xb (bf16) once; xb aliases t1 (dead until k_node1)
// ---------------------------------------------------------------------------
__global__ void __launch_bounds__(256) k_cast(
    const float* __restrict__ x, u16* __restrict__ xb)
{
  const long total = (long)NN * 16;
  for (long i = (long)blockIdx.x * 256 + threadIdx.x; i < total;
       i += (long)gridDim.x * 256) {
    f32x4 v0 = reinterpret_cast<const f32x4*>(x)[i * 2];
    f32x4 v1 = reinterpret_cast<const f32x4*>(x)[i * 2 + 1];
    reinterpret_cast<short8*>(xb)[i] = pack_bf16x8(v0, v1);
  }
}

// ---------------------------------------------------------------------------
// CSR build: histogram -> scan -> fill
// ---------------------------------------------------------------------------
__global__ void __launch_bounds__(256) k_hist(
    const int* __restrict__ eidx, int* __restrict__ deg)
{
  for (int e = blockIdx.x * 256 + threadIdx.x; e < EE; e += gridDim.x * 256)
    atomicAdd(&deg[eidx[EE + e]], 1);
}

__global__ void __launch_bounds__(256) k_bsum(
    const int* __restrict__ deg, int* __restrict__ bsum)
{
  const int t = threadIdx.x;
  int idx = blockIdx.x * 1024 + t * 4;
  int s = 0;
#pragma unroll
  for (int i = 0; i < 4; ++i) if (idx + i < NN) s += deg[idx + i];
#pragma unroll
  for (int m = 1; m < 64; m <<= 1) s += __shfl_xor(s, m);
  __shared__ int ws_[4];
  if ((t & 63) == 0) ws_[t >> 6] = s;
  __syncthreads();
  if (t == 0) bsum[blockIdx.x] = ws_[0] + ws_[1] + ws_[2] + ws_[3];
}

__global__ void k_scanb(int* __restrict__ bsum, int* __restrict__ start)
{
  if (threadIdx.x == 0 && blockIdx.x == 0) {
    int run = 0;
    for (int b = 0; b < 98; ++b) { int t = bsum[b]; bsum[b] = run; run += t; }
    start[NN] = EE;
  }
}

__global__ void __launch_bounds__(256) k_scanc(
    const int* __restrict__ deg, const int* __restrict__ bsum,
    int* __restrict__ start, int* __restrict__ cur)
{
  const int t = threadIdx.x, lane = t & 63, wv = t >> 6;
  int idx = blockIdx.x * 1024 + t * 4;
  int c[4], ts = 0;
#pragma unroll
  for (int i = 0; i < 4; ++i) { c[i] = (idx + i < NN) ? deg[idx + i] : 0; ts += c[i]; }
  int incl = ts;
#pragma unroll
  for (int d = 1; d < 64; d <<= 1) {
    int u = __shfl_up(incl, d);
    if (lane >= d) incl += u;
  }
  __shared__ int wsum[4];
  if (lane == 63) wsum[wv] = incl;
  __syncthreads();
  int base = bsum[blockIdx.x];
  for (int w = 0; w < wv; ++w) base += wsum[w];
  int run = base + incl - ts;
#pragma unroll
  for (int i = 0; i < 4; ++i) {
    if (idx + i < NN) { start[idx + i] = run; cur[idx + i] = run; }
    run += c[i];
  }
}

__global__ void __launch_bounds__(256) k_fill(
    const int* __restrict__ eidx, int* __restrict__ cur, int* __restrict__ sid)
{
  for (int e = blockIdx.x * 256 + threadIdx.x; e < EE; e += gridDim.x * 256) {
    int c = eidx[EE + e];
    int p = atomicAdd(&cur[c], 1);
    sid[p] = e;
  }
}

// ---------------------------------------------------------------------------
// K1: per-edge MLP  h = relu(LN(concat(x[row], ea) @ W1 + b1)) -> hbuf (bf16)
// Persistent WGs: 512 thr (8 waves), each wave owns a 16-edge MFMA tile.
// W1^T staged once per WG as fragment-linear LDS (zero-conflict reads).
// NO atomics.
// ---------------------------------------------------------------------------
__global__ void __launch_bounds__(512) k_edge(
    const u16* __restrict__ xb, const float* __restrict__ ea,
    const float* __restrict__ W1, const float* __restrict__ b1,
    const float* __restrict__ g1, const float* __restrict__ be1,
    const int* __restrict__ eidx, u16* __restrict__ hbuf)
{
  extern __shared__ char smem[];  // 65536 B: frag[nt][kc][lane] * 16B
  const int tid = threadIdx.x;

#pragma unroll
  for (int i = 0; i < 8; ++i) {
    int f = i * 512 + tid;             // 0..4095
    int lo_ = f & 15;
    int kb_ = (f >> 4) & 3;
    int kc_ = (f >> 6) & 7;
    int nt_ = f >> 9;
    int n = nt_ * 16 + lo_;
    int k0 = kc_ * 32 + kb_ * 8;
    bf16x8 p;
#pragma unroll
    for (int j = 0; j < 8; ++j) p[j] = (__bf16)W1[(k0 + j) * 128 + n];
    *reinterpret_cast<short8*>(smem + f * 16) = __builtin_bit_cast(short8, p);
  }

  const int lane = tid & 63;
  const int wv = tid >> 6;
  const int lo = lane & 15;
  const int kb = lane >> 4;

  float b1v[8], g1v[8], bev[8];
#pragma unroll
  for (int nt = 0; nt < 8; ++nt) {
    int c = nt * 16 + lo;
    b1v[nt] = b1[c]; g1v[nt] = g1[c]; bev[nt] = be1[c];
  }
  __syncthreads();

  for (int t = blockIdx.x; t < EE / 128; t += gridDim.x) {
    const int ebase = t * 128 + wv * 16;
    const int e = ebase + lo;
    const int r = eidx[e];

    short8 a[8];
#pragma unroll
    for (int kc = 0; kc < 4; ++kc)
      a[kc] = *reinterpret_cast<const short8*>(xb + (long)r * 128 + kc * 32 + kb * 8);
#pragma unroll
    for (int kc = 4; kc < 8; ++kc) {
      const float* src = ea + (long)e * 128 + (kc - 4) * 32 + kb * 8;
      f32x4 v0 = *reinterpret_cast<const f32x4*>(src);
      f32x4 v1 = *reinterpret_cast<const f32x4*>(src + 4);
      a[kc] = pack_bf16x8(v0, v1);
    }

    f32x4 acc[8];
#pragma unroll
    for (int nt = 0; nt < 8; ++nt) acc[nt] = (f32x4){0.f, 0.f, 0.f, 0.f};

#pragma unroll
    for (int nt = 0; nt < 8; ++nt)
#pragma unroll
      for (int kc = 0; kc < 8; ++kc) {
        short8 b = *reinterpret_cast<const short8*>(
            smem + nt * 8192 + kc * 1024 + lane * 16);
        acc[nt] = __builtin_amdgcn_mfma_f32_16x16x32_bf16(a[kc], b, acc[nt], 0, 0, 0);
      }

    // bias + LN stats (row = edge = kb*4+i, col = nt*16+lo)
    float s[4] = {0.f, 0.f, 0.f, 0.f};
    float q[4] = {0.f, 0.f, 0.f, 0.f};
#pragma unroll
    for (int nt = 0; nt < 8; ++nt)
#pragma unroll
      for (int i = 0; i < 4; ++i) {
        float v = acc[nt][i] + b1v[nt];
        acc[nt][i] = v;
        s[i] += v; q[i] += v * v;
      }
#pragma unroll
    for (int m = 1; m < 16; m <<= 1)
#pragma unroll
      for (int i = 0; i < 4; ++i) {
        s[i] += __shfl_xor(s[i], m);
        q[i] += __shfl_xor(q[i], m);
      }
    float mu[4], rs[4];
#pragma unroll
    for (int i = 0; i < 4; ++i) {
      mu[i] = s[i] * (1.f / 128.f);
      float var = q[i] * (1.f / 128.f) - mu[i] * mu[i];
      rs[i] = rsqrtf(var + 1e-5f);
    }
#pragma unroll
    for (int nt = 0; nt < 8; ++nt)
#pragma unroll
      for (int i = 0; i < 4; ++i) {
        float v = fmaxf((acc[nt][i] - mu[i]) * rs[i] * g1v[nt] + bev[nt], 0.f);
        float vn = __shfl_xor(v, 1);
        if (!(lo & 1)) {
          u32 pk = (u32)f2bf(v) | ((u32)f2bf(vn) << 16);
          *reinterpret_cast<u32*>(hbuf + (long)(ebase + kb * 4 + i) * 128 + nt * 16 + lo) = pk;
        }
      }
  }
}

// ---------------------------------------------------------------------------
// K2a: agg = gather-sum(hbuf over CSR); u = (1+eps)*x + agg;
// t1 = relu(LN(u @ W2 + b2)) stored bf16.  16 rows/wave, 64 rows/WG.
// ---------------------------------------------------------------------------
__global__ void __launch_bounds__(256) k_node1(
    const float* __restrict__ x, const u16* __restrict__ hbuf,
    const int* __restrict__ sid, const int* __restrict__ start,
    const float* __restrict__ W2, const float* __restrict__ b2,
    const float* __restrict__ g2, const float* __restrict__ be2,
    const float* __restrict__ epsp, u16* __restrict__ t1)
{
  __shared__ char smem[32768];  // frag[nt][kc][lane] * 16B
  const int tid = threadIdx.x;
#pragma unroll
  for (int i = 0; i < 8; ++i) {
    int f = i * 256 + tid;             // 0..2047
    int lo_ = f & 15;
    int kb_ = (f >> 4) & 3;
    int kc_ = (f >> 6) & 3;
    int nt_ = f >> 8;
    int n = nt_ * 16 + lo_;
    int k0 = kc_ * 32 + kb_ * 8;
    bf16x8 p;
#pragma unroll
    for (int j = 0; j < 8; ++j) p[j] = (__bf16)W2[(k0 + j) * 128 + n];
    *reinterpret_cast<short8*>(smem + f * 16) = __builtin_bit_cast(short8, p);
  }

  const int lane = tid & 63, wv = tid >> 6, lo = lane & 15, kb = lane >> 4;
  const float ope = 1.f + epsp[0];
  __syncthreads();

  const int row = blockIdx.x * 64 + wv * 16 + lo;
  const int rc = row < NN ? row : NN - 1;

  float uacc[4][8];
#pragma unroll
  for (int kc = 0; kc < 4; ++kc)
#pragma unroll
    for (int j = 0; j < 8; ++j) uacc[kc][j] = 0.f;

  const int p0 = start[rc], p1 = start[rc + 1];
  for (int p = p0; p < p1; ++p) {
    int eid = sid[p];
    const u16* hr = hbuf + (long)eid * 128 + kb * 8;
#pragma unroll
    for (int kc = 0; kc < 4; ++kc) {
      short8 hv = *reinterpret_cast<const short8*>(hr + kc * 32);
#pragma unroll
      for (int j = 0; j < 8; ++j) uacc[kc][j] += bf2f(hv[j]);
    }
  }

  short8 a[4];
#pragma unroll
  for (int kc = 0; kc < 4; ++kc) {
    const float* xp = x + (long)rc * 128 + kc * 32 + kb * 8;
    f32x4 x0 = *reinterpret_cast<const f32x4*>(xp);
    f32x4 x1 = *reinterpret_cast<const f32x4*>(xp + 4);
    f32x4 u0, u1;
#pragma unroll
    for (int j = 0; j < 4; ++j) {
      u0[j] = fmaf(x0[j], ope, uacc[kc][j]);
      u1[j] = fmaf(x1[j], ope, uacc[kc][4 + j]);
    }
    a[kc] = pack_bf16x8(u0, u1);
  }

  f32x4 acc[8];
#pragma unroll
  for (int nt = 0; nt < 8; ++nt) acc[nt] = (f32x4){0.f, 0.f, 0.f, 0.f};

#pragma unroll
  for (int nt = 0; nt < 8; ++nt)
#pragma unroll
    for (int kc = 0; kc < 4; ++kc) {
      short8 b = *reinterpret_cast<const short8*>(smem + nt * 4096 + kc * 1024 + lane * 16);
      acc[nt] = __builtin_amdgcn_mfma_f32_16x16x32_bf16(a[kc], b, acc[nt], 0, 0, 0);
    }

  float b2v[8], g2v[8], bev[8];
#pragma unroll
  for (int nt = 0; nt < 8; ++nt) {
    int c = nt * 16 + lo;
    b2v[nt] = b2[c]; g2v[nt] = g2[c]; bev[nt] = be2[c];
  }

  float s[4] = {0.f, 0.f, 0.f, 0.f};
  float q[4] = {0.f, 0.f, 0.f, 0.f};
#pragma unroll
  for (int nt = 0; nt < 8; ++nt)
#pragma unroll
    for (int i = 0; i < 4; ++i) {
      float v = acc[nt][i] + b2v[nt];
      acc[nt][i] = v;
      s[i] += v; q[i] += v * v;
    }
#pragma unroll
  for (int m = 1; m < 16; m <<= 1)
#pragma unroll
    for (int i = 0; i < 4; ++i) {
      s[i] += __shfl_xor(s[i], m);
      q[i] += __shfl_xor(q[i], m);
    }
  float mu[4], rs[4];
  int rows[4];
#pragma unroll
  for (int i = 0; i < 4; ++i) {
    mu[i] = s[i] * (1.f / 128.f);
    float var = q[i] * (1.f / 128.f) - mu[i] * mu[i];
    rs[i] = rsqrtf(var + 1e-5f);
    rows[i] = blockIdx.x * 64 + wv * 16 + kb * 4 + i;
  }
#pragma unroll
  for (int nt = 0; nt < 8; ++nt)
#pragma unroll
    for (int i = 0; i < 4; ++i) {
      float v = fmaxf((acc[nt][i] - mu[i]) * rs[i] * g2v[nt] + bev[nt], 0.f);
      float vn = __shfl_xor(v, 1);
      if (!(lo & 1) && rows[i] < NN) {
        u32 pk = (u32)f2bf(v) | ((u32)f2bf(vn) << 16);
        *reinterpret_cast<u32*>(t1 + (long)rows[i] * 128 + nt * 16 + lo) = pk;
      }
    }
}

// ---------------------------------------------------------------------------
// K2b: pre = t1 @ W3 + b3 + 2*x ; store f32 + per-WG column partial sums
// ---------------------------------------------------------------------------
__global__ void __launch_bounds__(256) k_node2(
    const u16* __restrict__ t1, const float* __restrict__ x,
    const float* __restrict__ W3, const float* __restrict__ b3,
    float* __restrict__ tmp, float* __restrict__ part)
{
  __shared__ char smem[32768];
  const int tid = threadIdx.x;
#pragma unroll
  for (int i = 0; i < 8; ++i) {
    int f = i * 256 + tid;
    int lo_ = f & 15;
    int kb_ = (f >> 4) & 3;
    int kc_ = (f >> 6) & 3;
    int nt_ = f >> 8;
    int n = nt_ * 16 + lo_;
    int k0 = kc_ * 32 + kb_ * 8;
    bf16x8 p;
#pragma unroll
    for (int j = 0; j < 8; ++j) p[j] = (__bf16)W3[(k0 + j) * 128 + n];
    *reinterpret_cast<short8*>(smem + f * 16) = __builtin_bit_cast(short8, p);
  }
  __syncthreads();

  const int lane = tid & 63, wv = tid >> 6, lo = lane & 15, kb = lane >> 4;
  const long rb = (long)blockIdx.x * 128 + wv * 32;

  short8 a[2][4];
#pragma unroll
  for (int mt = 0; mt < 2; ++mt) {
    long row = rb + mt * 16 + lo;
    long rc = row < NN ? row : (NN - 1);
#pragma unroll
    for (int kc = 0; kc < 4; ++kc)
      a[mt][kc] = *reinterpret_cast<const short8*>(t1 + rc * 128 + kc * 32 + kb * 8);
  }

  f32x4 acc[2][8];
#pragma unroll
  for (int mt = 0; mt < 2; ++mt)
#pragma unroll
    for (int nt = 0; nt < 8; ++nt)
      acc[mt][nt] = (f32x4){0.f, 0.f, 0.f, 0.f};

#pragma unroll
  for (int nt = 0; nt < 8; ++nt)
#pragma unroll
    for (int kc = 0; kc < 4; ++kc) {
      short8 b = *reinterpret_cast<const short8*>(smem + nt * 4096 + kc * 1024 + lane * 16);
      acc[0][nt] = __builtin_amdgcn_mfma_f32_16x16x32_bf16(a[0][kc], b, acc[0][nt], 0, 0, 0);
      acc[1][nt] = __builtin_amdgcn_mfma_f32_16x16x32_bf16(a[1][kc], b, acc[1][nt], 0, 0, 0);
    }

  float b3v[8];
#pragma unroll
  for (int nt = 0; nt < 8; ++nt) b3v[nt] = b3[nt * 16 + lo];

  float sn[8] = {0.f, 0.f, 0.f, 0.f, 0.f, 0.f, 0.f, 0.f};
  float qn[8] = {0.f, 0.f, 0.f, 0.f, 0.f, 0.f, 0.f, 0.f};

#pragma unroll
  for (int mt = 0; mt < 2; ++mt) {
    long rows[4], rc[4];
    bool val[4];
#pragma unroll
    for (int i = 0; i < 4; ++i) {
      rows[i] = rb + mt * 16 + kb * 4 + i;
      val[i] = rows[i] < NN;
      rc[i] = val[i] ? rows[i] : (NN - 1);
    }
#pragma unroll
    for (int nt = 0; nt < 8; ++nt)
#pragma unroll
      for (int i = 0; i < 4; ++i) {
        float v = acc[mt][nt][i] + b3v[nt] + 2.f * x[rc[i] * 128 + nt * 16 + lo];
        if (val[i]) {
          tmp[rows[i] * 128 + nt * 16 + lo] = v;
          sn[nt] += v; qn[nt] += v * v;
        }
      }
  }
#pragma unroll
  for (int nt = 0; nt < 8; ++nt) {
    sn[nt] += __shfl_xor(sn[nt], 16); sn[nt] += __shfl_xor(sn[nt], 32);
    qn[nt] += __shfl_xor(qn[nt], 16); qn[nt] += __shfl_xor(qn[nt], 32);
  }
  if (lane < 16) {
    long pr = ((long)blockIdx.x * 4 + wv) * 256;
#pragma unroll
    for (int nt = 0; nt < 8; ++nt) {
      part[pr + nt * 16 + lane] = sn[nt];
      part[pr + 128 + nt * 16 + lane] = qn[nt];
    }
  }
}

// ---------------------------------------------------------------------------
// K2c: reduce partials -> per-column scale/shift for BN
// ---------------------------------------------------------------------------
__global__ void __launch_bounds__(256) k_stats(
    const float* __restrict__ part, const float* __restrict__ bng,
    const float* __restrict__ bnb, float* __restrict__ stats2)
{
  const int c = blockIdx.x;
  const int tid = threadIdx.x;
  float s = 0.f, q = 0.f;
  for (int i = tid; i < 3128; i += 256) {
    s += part[(long)i * 256 + c];
    q += part[(long)i * 256 + 128 + c];
  }
#pragma unroll
  for (int m = 1; m < 64; m <<= 1) { s += __shfl_xor(s, m); q += __shfl_xor(q, m); }
  __shared__ float rs_[4], rq_[4];
  const int wv = tid >> 6;
  if ((tid & 63) == 0) { rs_[wv] = s; rq_[wv] = q; }
  __syncthreads();
  if (tid == 0) {
    s = rs_[0] + rs_[1] + rs_[2] + rs_[3];
    q = rq_[0] + rq_[1] + rq_[2] + rq_[3];
    float mu = s * (1.f / (float)NN);
    float var = q * (1.f / (float)NN) - mu * mu;
    float sc = rsqrtf(var + 1e-5f) * bng[c];
    stats2[c] = sc;
    stats2[128 + c] = bnb[c] - mu * sc;
  }
}

// ---------------------------------------------------------------------------
// K3: BN apply, f32 out
// ---------------------------------------------------------------------------
__global__ void __launch_bounds__(256) k_apply(
    const float* __restrict__ tmp, const float* __restrict__ stats2,
    float* __restrict__ out)
{
  const long total = (long)NN * 32;
  for (long i = (long)blockIdx.x * 256 + threadIdx.x; i < total;
       i += (long)gridDim.x * 256) {
    int db = (int)((i & 31) << 2);
    f32x4 v = reinterpret_cast<const f32x4*>(tmp)[i];
    f32x4 sc = *reinterpret_cast<const f32x4*>(stats2 + db);
    f32x4 sh = *reinterpret_cast<const f32x4*>(stats2 + 128 + db);
    f32x4 o;
#pragma unroll
    for (int j = 0; j < 4; ++j) o[j] = fmaf(v[j], sc[j], sh[j]);
    reinterpret_cast<f32x4*>(out)[i] = o;
  }
}

extern "C" void kernel_launch(void* const* d_in, const int* in_sizes, int n_in,
                              void* d_out, int out_size, void* d_ws, size_t ws_size,
                              hipStream_t stream)
{
  const float* x   = (const float*)d_in[0];
  const float* ea  = (const float*)d_in[1];
  const float* W1  = (const float*)d_in[2];
  const float* b1  = (const float*)d_in[3];
  const float* g1  = (const float*)d_in[4];
  const float* be1 = (const float*)d_in[5];
  const float* W2  = (const float*)d_in[6];
  const float* b2  = (const float*)d_in[7];
  const float* g2  = (const float*)d_in[8];
  const float* be2 = (const float*)d_in[9];
  const float* W3  = (const float*)d_in[10];
  const float* b3  = (const float*)d_in[11];
  const float* eps = (const float*)d_in[12];
  const float* bng = (const float*)d_in[13];
  const float* bnb = (const float*)d_in[14];
  const int*   eidx = (const int*)d_in[15];
  float* out = (float*)d_out;

  // workspace layout (bytes):
  // [0, 102.4M)   hbuf  u16[EE*128]     (later aliased by tmp f32[NN*128])
  // [102.4M,128M) t1    u16[NN*128]     (xb aliases this, dead before t1 write)
  // [128M, ...)   part, stats2, deg, start, cur, bsum, sid
  u16*   hbuf   = (u16*)d_ws;
  u16*   t1     = (u16*)((char*)d_ws + 102400000L);
  u16*   xb     = t1;
  float* tmp    = (float*)d_ws;                    // aliases hbuf (dead by k_node2)
  float* part   = (float*)((char*)d_ws + 128000000L);
  float* stats2 = part + 3128L * 256;
  int*   deg    = (int*)(stats2 + 256);
  int*   start  = deg + NN;
  int*   cur    = start + NN + 1;
  int*   bsum   = cur + NN;
  int*   sid    = bsum + 128;

  hipMemsetAsync(deg, 0, (size_t)NN * 4, stream);
  k_cast  <<<1024, 256, 0, stream>>>(x, xb);
  k_hist  <<<512, 256, 0, stream>>>(eidx, deg);
  k_bsum  <<<98, 256, 0, stream>>>(deg, bsum);
  k_scanb <<<1, 64, 0, stream>>>(bsum, start);
  k_scanc <<<98, 256, 0, stream>>>(deg, bsum, start, cur);
  k_fill  <<<512, 256, 0, stream>>>(eidx, cur, sid);
  k_edge  <<<1024, 512, 65536, stream>>>(xb, ea, W1, b1, g1, be1, eidx, hbuf);
  k_node1 <<<(NN + 63) / 64, 256, 0, stream>>>(x, hbuf, sid, start, W2, b2, g2, be2, eps, t1);
  k_node2 <<<(NN + 127) / 128, 256, 0, stream>>>(t1, x, W3, b3, tmp, part);
  k_stats <<<128, 256, 0, stream>>>(part, bng, bnb, stats2);
  k_apply <<<2048, 256, 0, stream>>>(tmp, stats2, out);
}

// Round 4
// 275.726 us; speedup vs baseline: 1.7329x; 1.7329x over previous
//
#include <hip/hip_runtime.h>

#define NN 100000
#define EE 400000

typedef unsigned short u16;
typedef unsigned int u32;
typedef short short8 __attribute__((ext_vector_type(8)));
typedef __bf16 bf16x8 __attribute__((ext_vector_type(8)));
typedef float f32x4 __attribute__((ext_vector_type(4)));

__device__ __forceinline__ short8 pack_bf16x8(f32x4 lo, f32x4 hi) {
  bf16x8 r;
#pragma unroll
  for (int j = 0; j < 4; ++j) { r[j] = (__bf16)lo[j]; r[4 + j] = (__bf16)hi[j]; }
  return __builtin_bit_cast(short8, r);
}

__device__ __forceinline__ u16 f2bf(float f) {
  return __builtin_bit_cast(unsigned short, (__bf16)f);
}

__device__ __forceinline__ float bf2f(short s) {
  u32 b = ((u32)(unsigned short)s) << 16;
  return __builtin_bit_cast(float, b);
}

// ---------------------------------------------------------------------------
// K0: cast x (f32) -> xb (bf16) once; xb aliases t1 (dead until k_node1)
// ---------------------------------------------------------------------------
__global__ void __launch_bounds__(256) k_cast(
    const float* __restrict__ x, u16* __restrict__ xb)
{
  const long total = (long)NN * 16;
  for (long i = (long)blockIdx.x * 256 + threadIdx.x; i < total;
       i += (long)gridDim.x * 256) {
    f32x4 v0 = reinterpret_cast<const f32x4*>(x)[i * 2];
    f32x4 v1 = reinterpret_cast<const f32x4*>(x)[i * 2 + 1];
    reinterpret_cast<short8*>(xb)[i] = pack_bf16x8(v0, v1);
  }
}

// ---------------------------------------------------------------------------
// CSR build: histogram -> scan -> fill
// ---------------------------------------------------------------------------
__global__ void __launch_bounds__(256) k_hist(
    const int* __restrict__ eidx, int* __restrict__ deg)
{
  for (int e = blockIdx.x * 256 + threadIdx.x; e < EE; e += gridDim.x * 256)
    atomicAdd(&deg[eidx[EE + e]], 1);
}

__global__ void __launch_bounds__(256) k_bsum(
    const int* __restrict__ deg, int* __restrict__ bsum)
{
  const int t = threadIdx.x;
  int idx = blockIdx.x * 1024 + t * 4;
  int s = 0;
#pragma unroll
  for (int i = 0; i < 4; ++i) if (idx + i < NN) s += deg[idx + i];
#pragma unroll
  for (int m = 1; m < 64; m <<= 1) s += __shfl_xor(s, m);
  __shared__ int ws_[4];
  if ((t & 63) == 0) ws_[t >> 6] = s;
  __syncthreads();
  if (t == 0) bsum[blockIdx.x] = ws_[0] + ws_[1] + ws_[2] + ws_[3];
}

__global__ void k_scanb(int* __restrict__ bsum, int* __restrict__ start)
{
  if (threadIdx.x == 0 && blockIdx.x == 0) {
    int run = 0;
    for (int b = 0; b < 98; ++b) { int t = bsum[b]; bsum[b] = run; run += t; }
    start[NN] = EE;
  }
}

__global__ void __launch_bounds__(256) k_scanc(
    const int* __restrict__ deg, const int* __restrict__ bsum,
    int* __restrict__ start, int* __restrict__ cur)
{
  const int t = threadIdx.x, lane = t & 63, wv = t >> 6;
  int idx = blockIdx.x * 1024 + t * 4;
  int c[4], ts = 0;
#pragma unroll
  for (int i = 0; i < 4; ++i) { c[i] = (idx + i < NN) ? deg[idx + i] : 0; ts += c[i]; }
  int incl = ts;
#pragma unroll
  for (int d = 1; d < 64; d <<= 1) {
    int u = __shfl_up(incl, d);
    if (lane >= d) incl += u;
  }
  __shared__ int wsum[4];
  if (lane == 63) wsum[wv] = incl;
  __syncthreads();
  int base = bsum[blockIdx.x];
  for (int w = 0; w < wv; ++w) base += wsum[w];
  int run = base + incl - ts;
#pragma unroll
  for (int i = 0; i < 4; ++i) {
    if (idx + i < NN) { start[idx + i] = run; cur[idx + i] = run; }
    run += c[i];
  }
}

__global__ void __launch_bounds__(256) k_fill(
    const int* __restrict__ eidx, int* __restrict__ cur, int* __restrict__ sid)
{
  for (int e = blockIdx.x * 256 + threadIdx.x; e < EE; e += gridDim.x * 256) {
    int c = eidx[EE + e];
    int p = atomicAdd(&cur[c], 1);
    sid[p] = e;
  }
}

// ---------------------------------------------------------------------------
// K1: per-edge MLP in CSR order: h = relu(LN(concat(x[row],ea)@W1+b1)) ->
// hbuf[p] (bf16, sorted position). LDS-transpose epilogue => full-line NT
// stores, zero write amplification. 512 thr, 8 waves, 16 edges/wave/tile.
// LDS: [0,64K) W1 fragments, [64K,96K) per-wave 4KB transpose buffers.
// ---------------------------------------------------------------------------
__global__ void __launch_bounds__(512) k_edge(
    const u16* __restrict__ xb, const float* __restrict__ ea,
    const float* __restrict__ W1, const float* __restrict__ b1,
    const float* __restrict__ g1, const float* __restrict__ be1,
    const int* __restrict__ eidx, const int* __restrict__ sid,
    u16* __restrict__ hbuf)
{
  extern __shared__ char smem[];
  const int tid = threadIdx.x;

  // Stage W1^T -> MFMA B-fragments, once per WG.
#pragma unroll
  for (int i = 0; i < 8; ++i) {
    int f = i * 512 + tid;             // 0..4095
    int lo_ = f & 15;
    int kb_ = (f >> 4) & 3;
    int kc_ = (f >> 6) & 7;
    int nt_ = f >> 9;
    int n = nt_ * 16 + lo_;
    int k0 = kc_ * 32 + kb_ * 8;
    bf16x8 p;
#pragma unroll
    for (int j = 0; j < 8; ++j) p[j] = (__bf16)W1[(k0 + j) * 128 + n];
    *reinterpret_cast<short8*>(smem + f * 16) = __builtin_bit_cast(short8, p);
  }

  const int lane = tid & 63;
  const int wv = tid >> 6;
  const int lo = lane & 15;
  const int kb = lane >> 4;
  char* tb = smem + 65536 + wv * 4096;   // u16[16][128] row-major, wave-private

  float b1v[8], g1v[8], bev[8];
#pragma unroll
  for (int nt = 0; nt < 8; ++nt) {
    int c = nt * 16 + lo;
    b1v[nt] = b1[c]; g1v[nt] = g1[c]; bev[nt] = be1[c];
  }
  __syncthreads();

  for (int t = blockIdx.x; t < EE / 128; t += gridDim.x) {
    const int pbase = t * 128 + wv * 16;   // sorted-position base of this tile
    const int p = pbase + lo;
    const int e = sid[p];
    const int r = eidx[e];

    short8 a[8];
#pragma unroll
    for (int kc = 0; kc < 4; ++kc)
      a[kc] = *reinterpret_cast<const short8*>(xb + (long)r * 128 + kc * 32 + kb * 8);
#pragma unroll
    for (int kc = 4; kc < 8; ++kc) {
      const float* src = ea + (long)e * 128 + (kc - 4) * 32 + kb * 8;
      f32x4 v0 = __builtin_nontemporal_load(reinterpret_cast<const f32x4*>(src));
      f32x4 v1 = __builtin_nontemporal_load(reinterpret_cast<const f32x4*>(src) + 1);
      a[kc] = pack_bf16x8(v0, v1);
    }

    f32x4 acc[8];
#pragma unroll
    for (int nt = 0; nt < 8; ++nt) acc[nt] = (f32x4){0.f, 0.f, 0.f, 0.f};

#pragma unroll
    for (int nt = 0; nt < 8; ++nt)
#pragma unroll
      for (int kc = 0; kc < 8; ++kc) {
        short8 b = *reinterpret_cast<const short8*>(
            smem + nt * 8192 + kc * 1024 + lane * 16);
        acc[nt] = __builtin_amdgcn_mfma_f32_16x16x32_bf16(a[kc], b, acc[nt], 0, 0, 0);
      }

    // bias + LN stats (local row = kb*4+i, col = nt*16+lo)
    float s[4] = {0.f, 0.f, 0.f, 0.f};
    float q[4] = {0.f, 0.f, 0.f, 0.f};
#pragma unroll
    for (int nt = 0; nt < 8; ++nt)
#pragma unroll
      for (int i = 0; i < 4; ++i) {
        float v = acc[nt][i] + b1v[nt];
        acc[nt][i] = v;
        s[i] += v; q[i] += v * v;
      }
#pragma unroll
    for (int m = 1; m < 16; m <<= 1)
#pragma unroll
      for (int i = 0; i < 4; ++i) {
        s[i] += __shfl_xor(s[i], m);
        q[i] += __shfl_xor(q[i], m);
      }
    float mu[4], rs[4];
#pragma unroll
    for (int i = 0; i < 4; ++i) {
      mu[i] = s[i] * (1.f / 128.f);
      float var = q[i] * (1.f / 128.f) - mu[i] * mu[i];
      rs[i] = rsqrtf(var + 1e-5f);
    }

    // LN+ReLU -> bf16 pairs -> LDS (fragment order in, row-major out)
#pragma unroll
    for (int nt = 0; nt < 8; ++nt)
#pragma unroll
      for (int i = 0; i < 4; ++i) {
        float v = fmaxf((acc[nt][i] - mu[i]) * rs[i] * g1v[nt] + bev[nt], 0.f);
        float vn = __shfl_xor(v, 1);
        if (!(lo & 1)) {
          u32 pk = (u32)f2bf(v) | ((u32)f2bf(vn) << 16);
          *reinterpret_cast<u32*>(tb + (kb * 4 + i) * 256 + (nt * 16 + lo) * 2) = pk;
        }
      }
    // Full-line stores: per instr 64 lanes x 16B = 4 complete rows (1KB).
#pragma unroll
    for (int s4 = 0; s4 < 4; ++s4) {
      short8 rv = *reinterpret_cast<const short8*>(
          tb + (s4 * 4 + (lane >> 4)) * 256 + (lane & 15) * 16);
      __builtin_nontemporal_store(rv,
          reinterpret_cast<short8*>(hbuf + ((long)pbase + s4 * 4 + (lane >> 4)) * 128
                                    + (lane & 15) * 8));
    }
  }
}

// ---------------------------------------------------------------------------
// K2a: agg = sum(hbuf[start[n]..start[n+1]]) (SEQUENTIAL rows now);
// u = (1+eps)*x + agg; t1 = relu(LN(u @ W2 + b2)) bf16.
// ---------------------------------------------------------------------------
__global__ void __launch_bounds__(256) k_node1(
    const float* __restrict__ x, const u16* __restrict__ hbuf,
    const int* __restrict__ start,
    const float* __restrict__ W2, const float* __restrict__ b2,
    const float* __restrict__ g2, const float* __restrict__ be2,
    const float* __restrict__ epsp, u16* __restrict__ t1)
{
  __shared__ char smem[32768];  // frag[nt][kc][lane] * 16B
  const int tid = threadIdx.x;
#pragma unroll
  for (int i = 0; i < 8; ++i) {
    int f = i * 256 + tid;             // 0..2047
    int lo_ = f & 15;
    int kb_ = (f >> 4) & 3;
    int kc_ = (f >> 6) & 3;
    int nt_ = f >> 8;
    int n = nt_ * 16 + lo_;
    int k0 = kc_ * 32 + kb_ * 8;
    bf16x8 p;
#pragma unroll
    for (int j = 0; j < 8; ++j) p[j] = (__bf16)W2[(k0 + j) * 128 + n];
    *reinterpret_cast<short8*>(smem + f * 16) = __builtin_bit_cast(short8, p);
  }

  const int lane = tid & 63, wv = tid >> 6, lo = lane & 15, kb = lane >> 4;
  const float ope = 1.f + epsp[0];
  __syncthreads();

  const int row = blockIdx.x * 64 + wv * 16 + lo;
  const int rc = row < NN ? row : NN - 1;

  float uacc[4][8];
#pragma unroll
  for (int kc = 0; kc < 4; ++kc)
#pragma unroll
    for (int j = 0; j < 8; ++j) uacc[kc][j] = 0.f;

  const int p0 = start[rc], p1 = start[rc + 1];
  for (int p = p0; p < p1; ++p) {
    const u16* hr = hbuf + (long)p * 128 + kb * 8;
#pragma unroll
    for (int kc = 0; kc < 4; ++kc) {
      short8 hv = __builtin_nontemporal_load(
          reinterpret_cast<const short8*>(hr + kc * 32));
#pragma unroll
      for (int j = 0; j < 8; ++j) uacc[kc][j] += bf2f(hv[j]);
    }
  }

  short8 a[4];
#pragma unroll
  for (int kc = 0; kc < 4; ++kc) {
    const float* xp = x + (long)rc * 128 + kc * 32 + kb * 8;
    f32x4 x0 = *reinterpret_cast<const f32x4*>(xp);
    f32x4 x1 = *reinterpret_cast<const f32x4*>(xp + 4);
    f32x4 u0, u1;
#pragma unroll
    for (int j = 0; j < 4; ++j) {
      u0[j] = fmaf(x0[j], ope, uacc[kc][j]);
      u1[j] = fmaf(x1[j], ope, uacc[kc][4 + j]);
    }
    a[kc] = pack_bf16x8(u0, u1);
  }

  f32x4 acc[8];
#pragma unroll
  for (int nt = 0; nt < 8; ++nt) acc[nt] = (f32x4){0.f, 0.f, 0.f, 0.f};

#pragma unroll
  for (int nt = 0; nt < 8; ++nt)
#pragma unroll
    for (int kc = 0; kc < 4; ++kc) {
      short8 b = *reinterpret_cast<const short8*>(smem + nt * 4096 + kc * 1024 + lane * 16);
      acc[nt] = __builtin_amdgcn_mfma_f32_16x16x32_bf16(a[kc], b, acc[nt], 0, 0, 0);
    }

  float b2v[8], g2v[8], bev[8];
#pragma unroll
  for (int nt = 0; nt < 8; ++nt) {
    int c = nt * 16 + lo;
    b2v[nt] = b2[c]; g2v[nt] = g2[c]; bev[nt] = be2[c];
  }

  float s[4] = {0.f, 0.f, 0.f, 0.f};
  float q[4] = {0.f, 0.f, 0.f, 0.f};
#pragma unroll
  for (int nt = 0; nt < 8; ++nt)
#pragma unroll
    for (int i = 0; i < 4; ++i) {
      float v = acc[nt][i] + b2v[nt];
      acc[nt][i] = v;
      s[i] += v; q[i] += v * v;
    }
#pragma unroll
  for (int m = 1; m < 16; m <<= 1)
#pragma unroll
    for (int i = 0; i < 4; ++i) {
      s[i] += __shfl_xor(s[i], m);
      q[i] += __shfl_xor(q[i], m);
    }
  float mu[4], rs[4];
  int rows[4];
#pragma unroll
  for (int i = 0; i < 4; ++i) {
    mu[i] = s[i] * (1.f / 128.f);
    float var = q[i] * (1.f / 128.f) - mu[i] * mu[i];
    rs[i] = rsqrtf(var + 1e-5f);
    rows[i] = blockIdx.x * 64 + wv * 16 + kb * 4 + i;
  }
#pragma unroll
  for (int nt = 0; nt < 8; ++nt)
#pragma unroll
    for (int i = 0; i < 4; ++i) {
      float v = fmaxf((acc[nt][i] - mu[i]) * rs[i] * g2v[nt] + bev[nt], 0.f);
      float vn = __shfl_xor(v, 1);
      if (!(lo & 1) && rows[i] < NN) {
        u32 pk = (u32)f2bf(v) | ((u32)f2bf(vn) << 16);
        *reinterpret_cast<u32*>(t1 + (long)rows[i] * 128 + nt * 16 + lo) = pk;
      }
    }
}

// ---------------------------------------------------------------------------
// K2b: pre = t1 @ W3 + b3 + 2*x ; store f32 + per-WG column partial sums
// ---------------------------------------------------------------------------
__global__ void __launch_bounds__(256) k_node2(
    const u16* __restrict__ t1, const float* __restrict__ x,
    const float* __restrict__ W3, const float* __restrict__ b3,
    float* __restrict__ tmp, float* __restrict__ part)
{
  __shared__ char smem[32768];
  const int tid = threadIdx.x;
#pragma unroll
  for (int i = 0; i < 8; ++i) {
    int f = i * 256 + tid;
    int lo_ = f & 15;
    int kb_ = (f >> 4) & 3;
    int kc_ = (f >> 6) & 3;
    int nt_ = f >> 8;
    int n = nt_ * 16 + lo_;
    int k0 = kc_ * 32 + kb_ * 8;
    bf16x8 p;
#pragma unroll
    for (int j = 0; j < 8; ++j) p[j] = (__bf16)W3[(k0 + j) * 128 + n];
    *reinterpret_cast<short8*>(smem + f * 16) = __builtin_bit_cast(short8, p);
  }
  __syncthreads();

  const int lane = tid & 63, wv = tid >> 6, lo = lane & 15, kb = lane >> 4;
  const long rb = (long)blockIdx.x * 128 + wv * 32;

  short8 a[2][4];
#pragma unroll
  for (int mt = 0; mt < 2; ++mt) {
    long row = rb + mt * 16 + lo;
    long rc = row < NN ? row : (NN - 1);
#pragma unroll
    for (int kc = 0; kc < 4; ++kc)
      a[mt][kc] = *reinterpret_cast<const short8*>(t1 + rc * 128 + kc * 32 + kb * 8);
  }

  f32x4 acc[2][8];
#pragma unroll
  for (int mt = 0; mt < 2; ++mt)
#pragma unroll
    for (int nt = 0; nt < 8; ++nt)
      acc[mt][nt] = (f32x4){0.f, 0.f, 0.f, 0.f};

#pragma unroll
  for (int nt = 0; nt < 8; ++nt)
#pragma unroll
    for (int kc = 0; kc < 4; ++kc) {
      short8 b = *reinterpret_cast<const short8*>(smem + nt * 4096 + kc * 1024 + lane * 16);
      acc[0][nt] = __builtin_amdgcn_mfma_f32_16x16x32_bf16(a[0][kc], b, acc[0][nt], 0, 0, 0);
      acc[1][nt] = __builtin_amdgcn_mfma_f32_16x16x32_bf16(a[1][kc], b, acc[1][nt], 0, 0, 0);
    }

  float b3v[8];
#pragma unroll
  for (int nt = 0; nt < 8; ++nt) b3v[nt] = b3[nt * 16 + lo];

  float sn[8] = {0.f, 0.f, 0.f, 0.f, 0.f, 0.f, 0.f, 0.f};
  float qn[8] = {0.f, 0.f, 0.f, 0.f, 0.f, 0.f, 0.f, 0.f};

#pragma unroll
  for (int mt = 0; mt < 2; ++mt) {
    long rows[4], rc[4];
    bool val[4];
#pragma unroll
    for (int i = 0; i < 4; ++i) {
      rows[i] = rb + mt * 16 + kb * 4 + i;
      val[i] = rows[i] < NN;
      rc[i] = val[i] ? rows[i] : (NN - 1);
    }
#pragma unroll
    for (int nt = 0; nt < 8; ++nt)
#pragma unroll
      for (int i = 0; i < 4; ++i) {
        float v = acc[mt][nt][i] + b3v[nt] + 2.f * x[rc[i] * 128 + nt * 16 + lo];
        if (val[i]) {
          tmp[rows[i] * 128 + nt * 16 + lo] = v;
          sn[nt] += v; qn[nt] += v * v;
        }
      }
  }
#pragma unroll
  for (int nt = 0; nt < 8; ++nt) {
    sn[nt] += __shfl_xor(sn[nt], 16); sn[nt] += __shfl_xor(sn[nt], 32);
    qn[nt] += __shfl_xor(qn[nt], 16); qn[nt] += __shfl_xor(qn[nt], 32);
  }
  if (lane < 16) {
    long pr = ((long)blockIdx.x * 4 + wv) * 256;
#pragma unroll
    for (int nt = 0; nt < 8; ++nt) {
      part[pr + nt * 16 + lane] = sn[nt];
      part[pr + 128 + nt * 16 + lane] = qn[nt];
    }
  }
}

// ---------------------------------------------------------------------------
// K2c: reduce partials -> per-column scale/shift for BN
// ---------------------------------------------------------------------------
__global__ void __launch_bounds__(256) k_stats(
    const float* __restrict__ part, const float* __restrict__ bng,
    const float* __restrict__ bnb, float* __restrict__ stats2)
{
  const int c = blockIdx.x;
  const int tid = threadIdx.x;
  float s = 0.f, q = 0.f;
  for (int i = tid; i < 3128; i += 256) {
    s += part[(long)i * 256 + c];
    q += part[(long)i * 256 + 128 + c];
  }
#pragma unroll
  for (int m = 1; m < 64; m <<= 1) { s += __shfl_xor(s, m); q += __shfl_xor(q, m); }
  __shared__ float rs_[4], rq_[4];
  const int wv = tid >> 6;
  if ((tid & 63) == 0) { rs_[wv] = s; rq_[wv] = q; }
  __syncthreads();
  if (tid == 0) {
    s = rs_[0] + rs_[1] + rs_[2] + rs_[3];
    q = rq_[0] + rq_[1] + rq_[2] + rq_[3];
    float mu = s * (1.f / (float)NN);
    float var = q * (1.f / (float)NN) - mu * mu;
    float sc = rsqrtf(var + 1e-5f) * bng[c];
    stats2[c] = sc;
    stats2[128 + c] = bnb[c] - mu * sc;
  }
}

// ---------------------------------------------------------------------------
// K3: BN apply, f32 out
// ---------------------------------------------------------------------------
__global__ void __launch_bounds__(256) k_apply(
    const float* __restrict__ tmp, const float* __restrict__ stats2,
    float* __restrict__ out)
{
  const long total = (long)NN * 32;
  for (long i = (long)blockIdx.x * 256 + threadIdx.x; i < total;
       i += (long)gridDim.x * 256) {
    int db = (int)((i & 31) << 2);
    f32x4 v = reinterpret_cast<const f32x4*>(tmp)[i];
    f32x4 sc = *reinterpret_cast<const f32x4*>(stats2 + db);
    f32x4 sh = *reinterpret_cast<const f32x4*>(stats2 + 128 + db);
    f32x4 o;
#pragma unroll
    for (int j = 0; j < 4; ++j) o[j] = fmaf(v[j], sc[j], sh[j]);
    reinterpret_cast<f32x4*>(out)[i] = o;
  }
}

extern "C" void kernel_launch(void* const* d_in, const int* in_sizes, int n_in,
                              void* d_out, int out_size, void* d_ws, size_t ws_size,
                              hipStream_t stream)
{
  const float* x   = (const float*)d_in[0];
  const float* ea  = (const float*)d_in[1];
  const float* W1  = (const float*)d_in[2];
  const float* b1  = (const float*)d_in[3];
  const float* g1  = (const float*)d_in[4];
  const float* be1 = (const float*)d_in[5];
  const float* W2  = (const float*)d_in[6];
  const float* b2  = (const float*)d_in[7];
  const float* g2  = (const float*)d_in[8];
  const float* be2 = (const float*)d_in[9];
  const float* W3  = (const float*)d_in[10];
  const float* b3  = (const float*)d_in[11];
  const float* eps = (const float*)d_in[12];
  const float* bng = (const float*)d_in[13];
  const float* bnb = (const float*)d_in[14];
  const int*   eidx = (const int*)d_in[15];
  float* out = (float*)d_out;

  // workspace layout (bytes):
  // [0, 102.4M)   hbuf  u16[EE*128]   (later aliased by tmp f32[NN*128])
  // [102.4M,...)  t1    u16[NN*128]   (xb aliases this, dead before t1 write)
  // [128M, ...)   part, stats2, deg, start, cur, bsum, sid
  u16*   hbuf   = (u16*)d_ws;
  u16*   t1     = (u16*)((char*)d_ws + 102400000L);
  u16*   xb     = t1;
  float* tmp    = (float*)d_ws;                    // aliases hbuf (dead by k_node2)
  float* part   = (float*)((char*)d_ws + 128000000L);
  float* stats2 = part + 3128L * 256;
  int*   deg    = (int*)(stats2 + 256);
  int*   start  = deg + NN;
  int*   cur    = start + NN + 1;
  int*   bsum   = cur + NN;
  int*   sid    = bsum + 128;

  // allow 96KB dynamic LDS for k_edge (harmless if already permitted)
  (void)hipFuncSetAttribute(reinterpret_cast<const void*>(k_edge),
                            hipFuncAttributeMaxDynamicSharedMemorySize, 98304);

  hipMemsetAsync(deg, 0, (size_t)NN * 4, stream);
  k_cast  <<<1024, 256, 0, stream>>>(x, xb);
  k_hist  <<<512, 256, 0, stream>>>(eidx, deg);
  k_bsum  <<<98, 256, 0, stream>>>(deg, bsum);
  k_scanb <<<1, 64, 0, stream>>>(bsum, start);
  k_scanc <<<98, 256, 0, stream>>>(deg, bsum, start, cur);
  k_fill  <<<512, 256, 0, stream>>>(eidx, cur, sid);
  k_edge  <<<256, 512, 98304, stream>>>(xb, ea, W1, b1, g1, be1, eidx, sid, hbuf);
  k_node1 <<<(NN + 63) / 64, 256, 0, stream>>>(x, hbuf, start, W2, b2, g2, be2, eps, t1);
  k_node2 <<<(NN + 127) / 128, 256, 0, stream>>>(t1, x, W3, b3, tmp, part);
  k_stats <<<128, 256, 0, stream>>>(part, bng, bnb, stats2);
  k_apply <<<2048, 256, 0, stream>>>(tmp, stats2, out);
}

// Round 5
// 269.585 us; speedup vs baseline: 1.7724x; 1.0228x over previous
//
#include <hip/hip_runtime.h>

#define NN 100000
#define EE 400000

typedef unsigned short u16;
typedef unsigned int u32;
typedef short short8 __attribute__((ext_vector_type(8)));
typedef __bf16 bf16x8 __attribute__((ext_vector_type(8)));
typedef float f32x4 __attribute__((ext_vector_type(4)));

__device__ __forceinline__ short8 pack_bf16x8(f32x4 lo, f32x4 hi) {
  bf16x8 r;
#pragma unroll
  for (int j = 0; j < 4; ++j) { r[j] = (__bf16)lo[j]; r[4 + j] = (__bf16)hi[j]; }
  return __builtin_bit_cast(short8, r);
}

__device__ __forceinline__ u16 f2bf(float f) {
  return __builtin_bit_cast(unsigned short, (__bf16)f);
}

__device__ __forceinline__ float bf2f(short s) {
  u32 b = ((u32)(unsigned short)s) << 16;
  return __builtin_bit_cast(float, b);
}

// ---------------------------------------------------------------------------
// K0: cast x (f32) -> xb (bf16) once; xb aliases t1 (dead until k_node1)
// ---------------------------------------------------------------------------
__global__ void __launch_bounds__(256) k_cast(
    const float* __restrict__ x, u16* __restrict__ xb)
{
  const long total = (long)NN * 16;
  for (long i = (long)blockIdx.x * 256 + threadIdx.x; i < total;
       i += (long)gridDim.x * 256) {
    f32x4 v0 = reinterpret_cast<const f32x4*>(x)[i * 2];
    f32x4 v1 = reinterpret_cast<const f32x4*>(x)[i * 2 + 1];
    reinterpret_cast<short8*>(xb)[i] = pack_bf16x8(v0, v1);
  }
}

// ---------------------------------------------------------------------------
// CSR build: histogram -> scan -> fill
// ---------------------------------------------------------------------------
__global__ void __launch_bounds__(256) k_hist(
    const int* __restrict__ eidx, int* __restrict__ deg)
{
  for (int e = blockIdx.x * 256 + threadIdx.x; e < EE; e += gridDim.x * 256)
    atomicAdd(&deg[eidx[EE + e]], 1);
}

__global__ void __launch_bounds__(256) k_bsum(
    const int* __restrict__ deg, int* __restrict__ bsum)
{
  const int t = threadIdx.x;
  int idx = blockIdx.x * 1024 + t * 4;
  int s = 0;
#pragma unroll
  for (int i = 0; i < 4; ++i) if (idx + i < NN) s += deg[idx + i];
#pragma unroll
  for (int m = 1; m < 64; m <<= 1) s += __shfl_xor(s, m);
  __shared__ int ws_[4];
  if ((t & 63) == 0) ws_[t >> 6] = s;
  __syncthreads();
  if (t == 0) bsum[blockIdx.x] = ws_[0] + ws_[1] + ws_[2] + ws_[3];
}

__global__ void k_scanb(int* __restrict__ bsum, int* __restrict__ start)
{
  if (threadIdx.x == 0 && blockIdx.x == 0) {
    int run = 0;
    for (int b = 0; b < 98; ++b) { int t = bsum[b]; bsum[b] = run; run += t; }
    start[NN] = EE;
  }
}

__global__ void __launch_bounds__(256) k_scanc(
    const int* __restrict__ deg, const int* __restrict__ bsum,
    int* __restrict__ start, int* __restrict__ cur)
{
  const int t = threadIdx.x, lane = t & 63, wv = t >> 6;
  int idx = blockIdx.x * 1024 + t * 4;
  int c[4], ts = 0;
#pragma unroll
  for (int i = 0; i < 4; ++i) { c[i] = (idx + i < NN) ? deg[idx + i] : 0; ts += c[i]; }
  int incl = ts;
#pragma unroll
  for (int d = 1; d < 64; d <<= 1) {
    int u = __shfl_up(incl, d);
    if (lane >= d) incl += u;
  }
  __shared__ int wsum[4];
  if (lane == 63) wsum[wv] = incl;
  __syncthreads();
  int base = bsum[blockIdx.x];
  for (int w = 0; w < wv; ++w) base += wsum[w];
  int run = base + incl - ts;
#pragma unroll
  for (int i = 0; i < 4; ++i) {
    if (idx + i < NN) { start[idx + i] = run; cur[idx + i] = run; }
    run += c[i];
  }
}

__global__ void __launch_bounds__(256) k_fill(
    const int* __restrict__ eidx, int* __restrict__ cur, int* __restrict__ sid)
{
  for (int e = blockIdx.x * 256 + threadIdx.x; e < EE; e += gridDim.x * 256) {
    int c = eidx[EE + e];
    int p = atomicAdd(&cur[c], 1);
    sid[p] = e;
  }
}

// ---------------------------------------------------------------------------
// K1: per-edge MLP in CSR order: h = relu(LN(concat(x[row],ea)@W1+b1)) ->
// hbuf[p] (bf16, sorted position). Two-pass LDS-transpose epilogue (2KB/wave,
// wave-private) => full-line NT stores AND 80KB total LDS -> 2 WG/CU.
// 512 thr, 8 waves, 16 edges/wave/tile.
// ---------------------------------------------------------------------------
__global__ void __launch_bounds__(512) k_edge(
    const u16* __restrict__ xb, const float* __restrict__ ea,
    const float* __restrict__ W1, const float* __restrict__ b1,
    const float* __restrict__ g1, const float* __restrict__ be1,
    const int* __restrict__ eidx, const int* __restrict__ sid,
    u16* __restrict__ hbuf)
{
  extern __shared__ char smem[];   // [0,64K) W1 frags; [64K,80K) 8x2KB wave tb
  const int tid = threadIdx.x;

  // Stage W1^T -> MFMA B-fragments, once per WG.
#pragma unroll
  for (int i = 0; i < 8; ++i) {
    int f = i * 512 + tid;             // 0..4095
    int lo_ = f & 15;
    int kb_ = (f >> 4) & 3;
    int kc_ = (f >> 6) & 7;
    int nt_ = f >> 9;
    int n = nt_ * 16 + lo_;
    int k0 = kc_ * 32 + kb_ * 8;
    bf16x8 p;
#pragma unroll
    for (int j = 0; j < 8; ++j) p[j] = (__bf16)W1[(k0 + j) * 128 + n];
    *reinterpret_cast<short8*>(smem + f * 16) = __builtin_bit_cast(short8, p);
  }

  const int lane = tid & 63;
  const int wv = tid >> 6;
  const int lo = lane & 15;
  const int kb = lane >> 4;
  char* tb = smem + 65536 + wv * 2048;   // u16[8][128] row-major, wave-private

  float b1v[8], g1v[8], bev[8];
#pragma unroll
  for (int nt = 0; nt < 8; ++nt) {
    int c = nt * 16 + lo;
    b1v[nt] = b1[c]; g1v[nt] = g1[c]; bev[nt] = be1[c];
  }
  __syncthreads();

  for (int t = blockIdx.x; t < EE / 128; t += gridDim.x) {
    const int pbase = t * 128 + wv * 16;   // sorted-position base of this tile
    const int p = pbase + lo;
    const int e = sid[p];
    const int r = eidx[e];

    short8 a[8];
#pragma unroll
    for (int kc = 0; kc < 4; ++kc)
      a[kc] = *reinterpret_cast<const short8*>(xb + (long)r * 128 + kc * 32 + kb * 8);
#pragma unroll
    for (int kc = 4; kc < 8; ++kc) {
      const float* src = ea + (long)e * 128 + (kc - 4) * 32 + kb * 8;
      f32x4 v0 = __builtin_nontemporal_load(reinterpret_cast<const f32x4*>(src));
      f32x4 v1 = __builtin_nontemporal_load(reinterpret_cast<const f32x4*>(src) + 1);
      a[kc] = pack_bf16x8(v0, v1);
    }

    f32x4 acc[8];
#pragma unroll
    for (int nt = 0; nt < 8; ++nt) acc[nt] = (f32x4){0.f, 0.f, 0.f, 0.f};

#pragma unroll
    for (int nt = 0; nt < 8; ++nt)
#pragma unroll
      for (int kc = 0; kc < 8; ++kc) {
        short8 b = *reinterpret_cast<const short8*>(
            smem + nt * 8192 + kc * 1024 + lane * 16);
        acc[nt] = __builtin_amdgcn_mfma_f32_16x16x32_bf16(a[kc], b, acc[nt], 0, 0, 0);
      }

    // bias + LN stats (local row = kb*4+i, col = nt*16+lo)
    float s[4] = {0.f, 0.f, 0.f, 0.f};
    float q[4] = {0.f, 0.f, 0.f, 0.f};
#pragma unroll
    for (int nt = 0; nt < 8; ++nt)
#pragma unroll
      for (int i = 0; i < 4; ++i) {
        float v = acc[nt][i] + b1v[nt];
        acc[nt][i] = v;
        s[i] += v; q[i] += v * v;
      }
#pragma unroll
    for (int m = 1; m < 16; m <<= 1)
#pragma unroll
      for (int i = 0; i < 4; ++i) {
        s[i] += __shfl_xor(s[i], m);
        q[i] += __shfl_xor(q[i], m);
      }
    float mu[4], rs[4];
#pragma unroll
    for (int i = 0; i < 4; ++i) {
      mu[i] = s[i] * (1.f / 128.f);
      float var = q[i] * (1.f / 128.f) - mu[i] * mu[i];
      rs[i] = rsqrtf(var + 1e-5f);
    }

    // LN+ReLU -> bf16 pairs (all lanes participate in shuffles)
    u32 pk[8][4];
#pragma unroll
    for (int nt = 0; nt < 8; ++nt)
#pragma unroll
      for (int i = 0; i < 4; ++i) {
        float v = fmaxf((acc[nt][i] - mu[i]) * rs[i] * g1v[nt] + bev[nt], 0.f);
        float vn = __shfl_xor(v, 1);
        pk[nt][i] = (u32)f2bf(v) | ((u32)f2bf(vn) << 16);
      }

    // Two-pass transpose through 2KB wave-private buffer.
#pragma unroll
    for (int h = 0; h < 2; ++h) {
      if (h) asm volatile("s_waitcnt lgkmcnt(0)" ::: "memory");
      if ((kb >> 1) == h && !(lo & 1)) {
        int rl = (kb & 1) * 4;
#pragma unroll
        for (int nt = 0; nt < 8; ++nt)
#pragma unroll
          for (int i = 0; i < 4; ++i)
            *reinterpret_cast<u32*>(tb + (rl + i) * 256 + (nt * 16 + lo) * 2) = pk[nt][i];
      }
#pragma unroll
      for (int s4 = 0; s4 < 2; ++s4) {
        short8 rv = *reinterpret_cast<const short8*>(
            tb + (s4 * 4 + (lane >> 4)) * 256 + (lane & 15) * 16);
        __builtin_nontemporal_store(rv,
            reinterpret_cast<short8*>(hbuf + ((long)pbase + h * 8 + s4 * 4 + (lane >> 4)) * 128
                                      + (lane & 15) * 8));
      }
    }
  }
}

// ---------------------------------------------------------------------------
// K2a: agg = sum(hbuf[start[n]..start[n+1]]) (sequential rows);
// u = (1+eps)*x + agg; t1 = relu(LN(u @ W2 + b2)) bf16.
// ---------------------------------------------------------------------------
__global__ void __launch_bounds__(256) k_node1(
    const float* __restrict__ x, const u16* __restrict__ hbuf,
    const int* __restrict__ start,
    const float* __restrict__ W2, const float* __restrict__ b2,
    const float* __restrict__ g2, const float* __restrict__ be2,
    const float* __restrict__ epsp, u16* __restrict__ t1)
{
  __shared__ char smem[32768];  // frag[nt][kc][lane] * 16B
  const int tid = threadIdx.x;
#pragma unroll
  for (int i = 0; i < 8; ++i) {
    int f = i * 256 + tid;             // 0..2047
    int lo_ = f & 15;
    int kb_ = (f >> 4) & 3;
    int kc_ = (f >> 6) & 3;
    int nt_ = f >> 8;
    int n = nt_ * 16 + lo_;
    int k0 = kc_ * 32 + kb_ * 8;
    bf16x8 p;
#pragma unroll
    for (int j = 0; j < 8; ++j) p[j] = (__bf16)W2[(k0 + j) * 128 + n];
    *reinterpret_cast<short8*>(smem + f * 16) = __builtin_bit_cast(short8, p);
  }

  const int lane = tid & 63, wv = tid >> 6, lo = lane & 15, kb = lane >> 4;
  const float ope = 1.f + epsp[0];
  __syncthreads();

  const int row = blockIdx.x * 64 + wv * 16 + lo;
  const int rc = row < NN ? row : NN - 1;

  float uacc[4][8];
#pragma unroll
  for (int kc = 0; kc < 4; ++kc)
#pragma unroll
    for (int j = 0; j < 8; ++j) uacc[kc][j] = 0.f;

  const int p0 = start[rc], p1 = start[rc + 1];
  for (int p = p0; p < p1; ++p) {
    const u16* hr = hbuf + (long)p * 128 + kb * 8;
#pragma unroll
    for (int kc = 0; kc < 4; ++kc) {
      short8 hv = __builtin_nontemporal_load(
          reinterpret_cast<const short8*>(hr + kc * 32));
#pragma unroll
      for (int j = 0; j < 8; ++j) uacc[kc][j] += bf2f(hv[j]);
    }
  }

  short8 a[4];
#pragma unroll
  for (int kc = 0; kc < 4; ++kc) {
    const float* xp = x + (long)rc * 128 + kc * 32 + kb * 8;
    f32x4 x0 = *reinterpret_cast<const f32x4*>(xp);
    f32x4 x1 = *reinterpret_cast<const f32x4*>(xp + 4);
    f32x4 u0, u1;
#pragma unroll
    for (int j = 0; j < 4; ++j) {
      u0[j] = fmaf(x0[j], ope, uacc[kc][j]);
      u1[j] = fmaf(x1[j], ope, uacc[kc][4 + j]);
    }
    a[kc] = pack_bf16x8(u0, u1);
  }

  f32x4 acc[8];
#pragma unroll
  for (int nt = 0; nt < 8; ++nt) acc[nt] = (f32x4){0.f, 0.f, 0.f, 0.f};

#pragma unroll
  for (int nt = 0; nt < 8; ++nt)
#pragma unroll
    for (int kc = 0; kc < 4; ++kc) {
      short8 b = *reinterpret_cast<const short8*>(smem + nt * 4096 + kc * 1024 + lane * 16);
      acc[nt] = __builtin_amdgcn_mfma_f32_16x16x32_bf16(a[kc], b, acc[nt], 0, 0, 0);
    }

  float b2v[8], g2v[8], bev[8];
#pragma unroll
  for (int nt = 0; nt < 8; ++nt) {
    int c = nt * 16 + lo;
    b2v[nt] = b2[c]; g2v[nt] = g2[c]; bev[nt] = be2[c];
  }

  float s[4] = {0.f, 0.f, 0.f, 0.f};
  float q[4] = {0.f, 0.f, 0.f, 0.f};
#pragma unroll
  for (int nt = 0; nt < 8; ++nt)
#pragma unroll
    for (int i = 0; i < 4; ++i) {
      float v = acc[nt][i] + b2v[nt];
      acc[nt][i] = v;
      s[i] += v; q[i] += v * v;
    }
#pragma unroll
  for (int m = 1; m < 16; m <<= 1)
#pragma unroll
    for (int i = 0; i < 4; ++i) {
      s[i] += __shfl_xor(s[i], m);
      q[i] += __shfl_xor(q[i], m);
    }
  float mu[4], rs[4];
  int rows[4];
#pragma unroll
  for (int i = 0; i < 4; ++i) {
    mu[i] = s[i] * (1.f / 128.f);
    float var = q[i] * (1.f / 128.f) - mu[i] * mu[i];
    rs[i] = rsqrtf(var + 1e-5f);
    rows[i] = blockIdx.x * 64 + wv * 16 + kb * 4 + i;
  }
#pragma unroll
  for (int nt = 0; nt < 8; ++nt)
#pragma unroll
    for (int i = 0; i < 4; ++i) {
      float v = fmaxf((acc[nt][i] - mu[i]) * rs[i] * g2v[nt] + bev[nt], 0.f);
      float vn = __shfl_xor(v, 1);
      if (!(lo & 1) && rows[i] < NN) {
        u32 pk = (u32)f2bf(v) | ((u32)f2bf(vn) << 16);
        *reinterpret_cast<u32*>(t1 + (long)rows[i] * 128 + nt * 16 + lo) = pk;
      }
    }
}

// ---------------------------------------------------------------------------
// K2b: pre = t1 @ W3 + b3 + 2*x ; store BF16 (pairs) + per-WG column partials
// ---------------------------------------------------------------------------
__global__ void __launch_bounds__(256) k_node2(
    const u16* __restrict__ t1, const float* __restrict__ x,
    const float* __restrict__ W3, const float* __restrict__ b3,
    u16* __restrict__ tmp, float* __restrict__ part)
{
  __shared__ char smem[32768];
  const int tid = threadIdx.x;
#pragma unroll
  for (int i = 0; i < 8; ++i) {
    int f = i * 256 + tid;
    int lo_ = f & 15;
    int kb_ = (f >> 4) & 3;
    int kc_ = (f >> 6) & 3;
    int nt_ = f >> 8;
    int n = nt_ * 16 + lo_;
    int k0 = kc_ * 32 + kb_ * 8;
    bf16x8 p;
#pragma unroll
    for (int j = 0; j < 8; ++j) p[j] = (__bf16)W3[(k0 + j) * 128 + n];
    *reinterpret_cast<short8*>(smem + f * 16) = __builtin_bit_cast(short8, p);
  }
  __syncthreads();

  const int lane = tid & 63, wv = tid >> 6, lo = lane & 15, kb = lane >> 4;
  const long rb = (long)blockIdx.x * 128 + wv * 32;

  short8 a[2][4];
#pragma unroll
  for (int mt = 0; mt < 2; ++mt) {
    long row = rb + mt * 16 + lo;
    long rc = row < NN ? row : (NN - 1);
#pragma unroll
    for (int kc = 0; kc < 4; ++kc)
      a[mt][kc] = *reinterpret_cast<const short8*>(t1 + rc * 128 + kc * 32 + kb * 8);
  }

  f32x4 acc[2][8];
#pragma unroll
  for (int mt = 0; mt < 2; ++mt)
#pragma unroll
    for (int nt = 0; nt < 8; ++nt)
      acc[mt][nt] = (f32x4){0.f, 0.f, 0.f, 0.f};

#pragma unroll
  for (int nt = 0; nt < 8; ++nt)
#pragma unroll
    for (int kc = 0; kc < 4; ++kc) {
      short8 b = *reinterpret_cast<const short8*>(smem + nt * 4096 + kc * 1024 + lane * 16);
      acc[0][nt] = __builtin_amdgcn_mfma_f32_16x16x32_bf16(a[0][kc], b, acc[0][nt], 0, 0, 0);
      acc[1][nt] = __builtin_amdgcn_mfma_f32_16x16x32_bf16(a[1][kc], b, acc[1][nt], 0, 0, 0);
    }

  float b3v[8];
#pragma unroll
  for (int nt = 0; nt < 8; ++nt) b3v[nt] = b3[nt * 16 + lo];

  float sn[8] = {0.f, 0.f, 0.f, 0.f, 0.f, 0.f, 0.f, 0.f};
  float qn[8] = {0.f, 0.f, 0.f, 0.f, 0.f, 0.f, 0.f, 0.f};

#pragma unroll
  for (int mt = 0; mt < 2; ++mt) {
    long rows[4], rc[4];
    bool val[4];
#pragma unroll
    for (int i = 0; i < 4; ++i) {
      rows[i] = rb + mt * 16 + kb * 4 + i;
      val[i] = rows[i] < NN;
      rc[i] = val[i] ? rows[i] : (NN - 1);
    }
#pragma unroll
    for (int nt = 0; nt < 8; ++nt)
#pragma unroll
      for (int i = 0; i < 4; ++i) {
        float v = acc[mt][nt][i] + b3v[nt] + 2.f * x[rc[i] * 128 + nt * 16 + lo];
        if (val[i]) { sn[nt] += v; qn[nt] += v * v; }
        float vn = __shfl_xor(v, 1);
        if (!(lo & 1) && val[i]) {
          u32 pk = (u32)f2bf(v) | ((u32)f2bf(vn) << 16);
          *reinterpret_cast<u32*>(tmp + rows[i] * 128 + nt * 16 + lo) = pk;
        }
      }
  }
#pragma unroll
  for (int nt = 0; nt < 8; ++nt) {
    sn[nt] += __shfl_xor(sn[nt], 16); sn[nt] += __shfl_xor(sn[nt], 32);
    qn[nt] += __shfl_xor(qn[nt], 16); qn[nt] += __shfl_xor(qn[nt], 32);
  }
  if (lane < 16) {
    long pr = ((long)blockIdx.x * 4 + wv) * 256;
#pragma unroll
    for (int nt = 0; nt < 8; ++nt) {
      part[pr + nt * 16 + lane] = sn[nt];
      part[pr + 128 + nt * 16 + lane] = qn[nt];
    }
  }
}

// ---------------------------------------------------------------------------
// K2c: reduce partials -> per-column scale/shift for BN
// ---------------------------------------------------------------------------
__global__ void __launch_bounds__(256) k_stats(
    const float* __restrict__ part, const float* __restrict__ bng,
    const float* __restrict__ bnb, float* __restrict__ stats2)
{
  const int c = blockIdx.x;
  const int tid = threadIdx.x;
  float s = 0.f, q = 0.f;
  for (int i = tid; i < 3128; i += 256) {
    s += part[(long)i * 256 + c];
    q += part[(long)i * 256 + 128 + c];
  }
#pragma unroll
  for (int m = 1; m < 64; m <<= 1) { s += __shfl_xor(s, m); q += __shfl_xor(q, m); }
  __shared__ float rs_[4], rq_[4];
  const int wv = tid >> 6;
  if ((tid & 63) == 0) { rs_[wv] = s; rq_[wv] = q; }
  __syncthreads();
  if (tid == 0) {
    s = rs_[0] + rs_[1] + rs_[2] + rs_[3];
    q = rq_[0] + rq_[1] + rq_[2] + rq_[3];
    float mu = s * (1.f / (float)NN);
    float var = q * (1.f / (float)NN) - mu * mu;
    float sc = rsqrtf(var + 1e-5f) * bng[c];
    stats2[c] = sc;
    stats2[128 + c] = bnb[c] - mu * sc;
  }
}

// ---------------------------------------------------------------------------
// K3: BN apply: tmp (bf16) -> out (f32)
// ---------------------------------------------------------------------------
__global__ void __launch_bounds__(256) k_apply(
    const u16* __restrict__ tmp, const float* __restrict__ stats2,
    float* __restrict__ out)
{
  const long total = (long)NN * 16;  // groups of 8 elems
  for (long i = (long)blockIdx.x * 256 + threadIdx.x; i < total;
       i += (long)gridDim.x * 256) {
    int db = (int)((i & 15) << 3);
    short8 hv = reinterpret_cast<const short8*>(tmp)[i];
    f32x4 sc0 = *reinterpret_cast<const f32x4*>(stats2 + db);
    f32x4 sc1 = *reinterpret_cast<const f32x4*>(stats2 + db + 4);
    f32x4 sh0 = *reinterpret_cast<const f32x4*>(stats2 + 128 + db);
    f32x4 sh1 = *reinterpret_cast<const f32x4*>(stats2 + 128 + db + 4);
    f32x4 o0, o1;
#pragma unroll
    for (int j = 0; j < 4; ++j) {
      o0[j] = fmaf(bf2f(hv[j]), sc0[j], sh0[j]);
      o1[j] = fmaf(bf2f(hv[4 + j]), sc1[j], sh1[j]);
    }
    reinterpret_cast<f32x4*>(out)[i * 2] = o0;
    reinterpret_cast<f32x4*>(out)[i * 2 + 1] = o1;
  }
}

extern "C" void kernel_launch(void* const* d_in, const int* in_sizes, int n_in,
                              void* d_out, int out_size, void* d_ws, size_t ws_size,
                              hipStream_t stream)
{
  const float* x   = (const float*)d_in[0];
  const float* ea  = (const float*)d_in[1];
  const float* W1  = (const float*)d_in[2];
  const float* b1  = (const float*)d_in[3];
  const float* g1  = (const float*)d_in[4];
  const float* be1 = (const float*)d_in[5];
  const float* W2  = (const float*)d_in[6];
  const float* b2  = (const float*)d_in[7];
  const float* g2  = (const float*)d_in[8];
  const float* be2 = (const float*)d_in[9];
  const float* W3  = (const float*)d_in[10];
  const float* b3  = (const float*)d_in[11];
  const float* eps = (const float*)d_in[12];
  const float* bng = (const float*)d_in[13];
  const float* bnb = (const float*)d_in[14];
  const int*   eidx = (const int*)d_in[15];
  float* out = (float*)d_out;

  // workspace layout (bytes):
  // [0, 102.4M)   hbuf u16[EE*128]  (later aliased by tmp u16[NN*128])
  // [102.4M,...)  t1   u16[NN*128]  (xb aliases this, dead before t1 write)
  // [128M, ...)   part, stats2, deg, start, cur, bsum, sid
  u16*   hbuf   = (u16*)d_ws;
  u16*   t1     = (u16*)((char*)d_ws + 102400000L);
  u16*   xb     = t1;
  u16*   tmp    = (u16*)d_ws;                      // aliases hbuf (dead by k_node2)
  float* part   = (float*)((char*)d_ws + 128000000L);
  float* stats2 = part + 3128L * 256;
  int*   deg    = (int*)(stats2 + 256);
  int*   start  = deg + NN;
  int*   cur    = start + NN + 1;
  int*   bsum   = cur + NN;
  int*   sid    = bsum + 128;

  (void)hipFuncSetAttribute(reinterpret_cast<const void*>(k_edge),
                            hipFuncAttributeMaxDynamicSharedMemorySize, 81920);

  hipMemsetAsync(deg, 0, (size_t)NN * 4, stream);
  k_cast  <<<1024, 256, 0, stream>>>(x, xb);
  k_hist  <<<512, 256, 0, stream>>>(eidx, deg);
  k_bsum  <<<98, 256, 0, stream>>>(deg, bsum);
  k_scanb <<<1, 64, 0, stream>>>(bsum, start);
  k_scanc <<<98, 256, 0, stream>>>(deg, bsum, start, cur);
  k_fill  <<<512, 256, 0, stream>>>(eidx, cur, sid);
  k_edge  <<<512, 512, 81920, stream>>>(xb, ea, W1, b1, g1, be1, eidx, sid, hbuf);
  k_node1 <<<(NN + 63) / 64, 256, 0, stream>>>(x, hbuf, start, W2, b2, g2, be2, eps, t1);
  k_node2 <<<(NN + 127) / 128, 256, 0, stream>>>(t1, x, W3, b3, tmp, part);
  k_stats <<<128, 256, 0, stream>>>(part, bng, bnb, stats2);
  k_apply <<<2048, 256, 0, stream>>>(tmp, stats2, out);
}